// Round 3
// baseline (1299.802 us; speedup 1.0000x reference)
//
#include <hip/hip_runtime.h>
#include <hip/hip_bf16.h>
#include <hip/hip_cooperative_groups.h>

namespace cg = cooperative_groups;

#define BB 2
#define NN 2048
#define DD 128
#define BN (BB*NN)
#define CAP 128
#define TD 16
#define QSTR 256
#define SSTR 128
#define INV_SQRT_D 0.08838834764831845f

typedef __attribute__((ext_vector_type(8))) short short8;
typedef __attribute__((ext_vector_type(4))) float f32x4;

struct MegaArgs {
    const float *node, *edge, *A;
    const float *Wq0, *Wk0, *Wv0, *We0, *Ws0;
    const float *Wq1, *Wk1, *Wv1, *We1, *Ws1;
    const float *Wq2, *Wk2, *Wv2, *We2, *Ws2;
    float *q, *s, *kA, *vA, *kB, *vB;
    __hip_bfloat16 *Wt1, *Wt2;
    float *out;
};

// ---------------------------------------------------------------------------
// One layer application: sparse attention (CSR in LDS) + optional fused
// next-layer MFMA projection. Body identical to the verified round-2 kernel;
// jc/ev/dg now come from block-persistent LDS.
//   NCOLS == 0 -> final layer, write fp32 to out.
// ---------------------------------------------------------------------------
template<int H, bool MEANH, bool LNRELU, int NCOLS, int HDN, int KVSI, int KVSO>
__device__ inline void layer_app(
    float* qio,                                   // in/out, stride QSTR (own rows)
    const float* __restrict__ k,                  // stride KVSI
    const float* __restrict__ v,                  // stride KVSI
    float* sio,                                   // in/out, stride SSTR (own rows)
    const float* __restrict__ We,
    const __hip_bfloat16* __restrict__ Wt,
    float* __restrict__ kn, float* __restrict__ vn,   // stride KVSO (own rows)
    float* __restrict__ out,
    int dg, const int* jc, const float* ev,
    int row0, int row, int wid, int lane,
    __hip_bfloat16 (*xs)[136])
{
    const int HD = H * DD;
    int sub = lane >> 4;
    int s   = lane & 15;
    int c0  = lane * 2;

    float qh[H][8];
    float qeI[H];
#pragma unroll
    for (int h = 0; h < H; h++) {
        const float* qp = &qio[(size_t)row * QSTR + h * DD + s * 8];
        const float* wp = &We[h * DD + s * 8];
        float pe = 0.f;
#pragma unroll
        for (int t = 0; t < 8; t++) { qh[h][t] = qp[t]; pe += qp[t] * wp[t]; }
#pragma unroll
        for (int off = 1; off < 16; off <<= 1) pe += __shfl_xor(pe, off);
        qeI[h] = pe * INV_SQRT_D;
    }

    float l_acc[H], ew_acc[H], acc[H][2];
#pragma unroll
    for (int h = 0; h < H; h++) { l_acc[h] = 0.f; ew_acc[h] = 0.f; acc[h][0] = 0.f; acc[h][1] = 0.f; }

    for (int m0 = 0; m0 < dg; m0 += 4) {
        int   e  = m0 + sub;
        bool  ok = e < dg;
        int   ec = ok ? e : m0;
        int   j  = jc[ec];
        float ee = ev[ec];

        int jb[4];
#pragma unroll
        for (int es = 0; es < 4; es++) jb[es] = jc[(m0 + es < dg) ? m0 + es : m0];
        float2 vv[H][4];
#pragma unroll
        for (int h = 0; h < H; h++)
#pragma unroll
            for (int es = 0; es < 4; es++)
                vv[h][es] = *(const float2*)&v[(size_t)jb[es] * KVSI + h * DD + c0];

#pragma unroll
        for (int h = 0; h < H; h++) {
            const float* kr = &k[(size_t)j * KVSI + h * DD + s * 8];
            float4 k0 = *(const float4*)kr;
            float4 k1 = *(const float4*)(kr + 4);
            float p = qh[h][0]*k0.x + qh[h][1]*k0.y + qh[h][2]*k0.z + qh[h][3]*k0.w
                    + qh[h][4]*k1.x + qh[h][5]*k1.y + qh[h][6]*k1.z + qh[h][7]*k1.w;
#pragma unroll
            for (int off = 1; off < 16; off <<= 1) p += __shfl_xor(p, off);
            float sc = ok ? (p * INV_SQRT_D + qeI[h] * ee) : -1e30f;
            float a4 = __expf(fminf(sc, 60.f));       // invalid -> exp(-1e30)=0
            l_acc[h]  += a4;                          // subgroup-local (x16 replicated)
            ew_acc[h] += a4 * ee;
            float al[4];
#pragma unroll
            for (int es = 0; es < 4; es++) al[es] = __shfl(a4, es * 16);
#pragma unroll
            for (int es = 0; es < 4; es++) {
                acc[h][0] += al[es] * vv[h][es].x;
                acc[h][1] += al[es] * vv[h][es].y;
            }
        }
    }

    // reduce l/ew across the 4 subgroups (values replicated within subgroup)
    float rh[H][2];
#pragma unroll
    for (int h = 0; h < H; h++) {
        float l  = l_acc[h]  + __shfl_xor(l_acc[h], 16);
        float ew = ew_acc[h] + __shfl_xor(ew_acc[h], 16);
        l  += __shfl_xor(l, 32);
        ew += __shfl_xor(ew, 32);
        float invZ = (l > 0.f) ? 1.f / l : 0.f;
        rh[h][0] = (acc[h][0] + ew * We[h * DD + c0])     * invZ;
        rh[h][1] = (acc[h][1] + ew * We[h * DD + c0 + 1]) * invZ;
    }
    float r0, r1;
    if constexpr (MEANH) {
        r0 = 0.5f * (rh[0][0] + rh[H - 1][0]);
        r1 = 0.5f * (rh[0][1] + rh[H - 1][1]);
    } else {
        r0 = rh[0][0]; r1 = rh[0][1];
    }
    float2 sk = *(const float2*)&sio[(size_t)row * SSTR + c0];
    r0 += sk.x; r1 += sk.y;

    if constexpr (LNRELU) {
        float sum = r0 + r1, sq = r0 * r0 + r1 * r1;
#pragma unroll
        for (int off = 32; off; off >>= 1) { sum += __shfl_xor(sum, off); sq += __shfl_xor(sq, off); }
        float mu  = sum * (1.f / DD);
        float var = sq * (1.f / DD) - mu * mu;
        float rs  = rsqrtf(var + 1e-5f);
        r0 = fmaxf((r0 - mu) * rs, 0.f);
        r1 = fmaxf((r1 - mu) * rs, 0.f);
    }

    if constexpr (NCOLS == 0) {
        float2 res; res.x = r0; res.y = r1;
        *(float2*)&out[(size_t)row * DD + c0] = res;
    } else {
        // stage bf16 x-tile in LDS, then MFMA-project into next-layer buffers
        __hip_bfloat162 o;
        o.x = __float2bfloat16(r0);
        o.y = __float2bfloat16(r1);
        *(__hip_bfloat162*)&xs[wid][c0] = o;
        __syncthreads();   // all attn reads of this block drained before use

        int m16 = lane & 15, quad = lane >> 4;
        short8 a[4];
#pragma unroll
        for (int ks = 0; ks < 4; ks++)
            a[ks] = *(const short8*)&xs[m16][ks * 32 + quad * 8];

#pragma unroll 1
        for (int tile = wid; tile < NCOLS / 16; tile += 16) {
            int n0 = tile * 16;
            float* o_; int lc; int od;
            if      (n0 < HDN)     { o_ = qio; lc = n0;           od = QSTR; }
            else if (n0 < 2*HDN)   { o_ = kn;  lc = n0 - HDN;     od = KVSO; }
            else if (n0 < 3*HDN)   { o_ = vn;  lc = n0 - 2*HDN;   od = KVSO; }
            else                   { o_ = sio; lc = n0 - 3*HDN;   od = SSTR; }
            f32x4 pacc = {0.f, 0.f, 0.f, 0.f};
#pragma unroll
            for (int ks = 0; ks < 4; ks++) {
                const short8* bp = (const short8*)&Wt[(size_t)(n0 + m16) * DD + ks * 32 + quad * 8];
                pacc = __builtin_amdgcn_mfma_f32_16x16x32_bf16(a[ks], *bp, pacc, 0, 0, 0);
            }
#pragma unroll
            for (int r = 0; r < 4; r++)
                o_[(size_t)(row0 + quad * 4 + r) * od + lc + m16] = pacc[r];
        }
    }
}

// ---------------------------------------------------------------------------
// Cooperative mega-kernel: CSR build (LDS-resident, never global) + weight
// prep + layer-0 projection + all 7 layer applications with grid.sync()
// between them. Grid = 256 blocks x 1024 threads = 1 block/CU (co-residency
// safe: <=128 VGPR via launch_bounds, ~20.4 KB LDS).
// ---------------------------------------------------------------------------
__global__ __launch_bounds__(1024) void mega(MegaArgs a)
{
    cg::grid_group grid = cg::this_grid();

    __shared__ int            jc_s[TD][CAP];
    __shared__ float          ev_s[TD][CAP];
    __shared__ __hip_bfloat16 xs[TD][136];   // +8 bf16 pad (16B-aligned rows)
    __shared__ int   cnt[TD];
    __shared__ int   dgs[TD];
    __shared__ float xnode[TD];

    int tid  = threadIdx.x;
    int bid  = blockIdx.x;
    int wid  = tid >> 6;
    int lane = tid & 63;
    int b    = bid >> 7;             // bid / (NN/TD)
    int dst0 = (bid & 127) * TD;
    int row0 = bid * TD;
    int row  = row0 + wid;

    // ---- phase A: CSR build for this block's 16 dst rows, into LDS ----
    if (tid < TD) cnt[tid] = 0;
    __syncthreads();
    {
        int srcOff = tid >> 2;               // 0..255
        int dOff   = (tid & 3) * 4;
        const size_t base = (size_t)b * NN * NN + dst0 + dOff;
#pragma unroll 2
        for (int s0 = 0; s0 < NN; s0 += 256) {
            int src = s0 + srcOff;
            float4 a4 = *(const float4*)&a.A[base + (size_t)src * NN];
            float4 e4 = *(const float4*)&a.edge[base + (size_t)src * NN];
            int gsrc = b * NN + src;
            float av[4] = {a4.x, a4.y, a4.z, a4.w};
            float ev[4] = {e4.x, e4.y, e4.z, e4.w};
#pragma unroll
            for (int u = 0; u < 4; u++) {
                if (av[u] != 0.f) {
                    int d = dOff + u;
                    int slot = atomicAdd(&cnt[d], 1);
                    if (slot < CAP) { jc_s[d][slot] = gsrc; ev_s[d][slot] = ev[u] * av[u]; }
                }
            }
        }
    }
    __syncthreads();
    if (tid < TD) dgs[tid] = min(cnt[tid], CAP);
    if (tid < TD) xnode[tid] = a.node[row0 + tid];
    __syncthreads();

    // ---- phase B: weight transposes (distributed) + layer-0 projection ----
    for (int c = bid; c < 1408; c += 256) {
        if (tid < DD) {
            const float *Wq, *Wk, *Wv, *Ws; __hip_bfloat16* Wt; int n, HD;
            if (c < 512) { Wq = a.Wq1; Wk = a.Wk1; Wv = a.Wv1; Ws = a.Ws1; Wt = a.Wt1; n = c;       HD = DD;     }
            else         { Wq = a.Wq2; Wk = a.Wk2; Wv = a.Wv2; Ws = a.Ws2; Wt = a.Wt2; n = c - 512; HD = 2 * DD; }
            const float* src; int ld; int col;
            if      (n < HD)     { src = Wq; col = n;          ld = HD; }
            else if (n < 2*HD)   { src = Wk; col = n - HD;     ld = HD; }
            else if (n < 3*HD)   { src = Wv; col = n - 2*HD;   ld = HD; }
            else                 { src = Ws; col = n - 3*HD;   ld = DD; }
            Wt[(size_t)n * DD + tid] = __float2bfloat16(src[(size_t)tid * ld + col]);
        }
    }
    // layer-0 rank-1 projection for this block's 16 rows, all 512 cols
    for (int i = tid; i < TD * 512; i += 1024) {
        int r = i >> 9, col = i & 511;
        float xv = xnode[r];
        const float* W; float* o; int lcol; int ostr;
        if      (col < DD)     { W = a.Wq0; o = a.q;  ostr = QSTR; lcol = col;          }
        else if (col < 2*DD)   { W = a.Wk0; o = a.kA; ostr = 256;  lcol = col - DD;     }
        else if (col < 3*DD)   { W = a.Wv0; o = a.vA; ostr = 256;  lcol = col - 2*DD;   }
        else                   { W = a.Ws0; o = a.s;  ostr = SSTR; lcol = col - 3*DD;   }
        o[(size_t)(row0 + r) * ostr + lcol] = xv * W[lcol];
    }

    __threadfence(); grid.sync();

    const int* jc = jc_s[wid];
    const float* ev = ev_s[wid];
    int dg = dgs[wid];

    // ---- 7 layer applications: l = {0,1,2,1,2,1,2} ----
    layer_app<1, false, true, 512, 128, 256, 128>(a.q, a.kA, a.vA, a.s, a.We0, a.Wt1,
        a.kB, a.vB, nullptr, dg, jc, ev, row0, row, wid, lane, xs);
    __threadfence(); grid.sync();

    layer_app<1, false, true, 896, 256, 128, 256>(a.q, a.kB, a.vB, a.s, a.We1, a.Wt2,
        a.kA, a.vA, nullptr, dg, jc, ev, row0, row, wid, lane, xs);
    __threadfence(); grid.sync();

    layer_app<2, true, false, 512, 128, 256, 128>(a.q, a.kA, a.vA, a.s, a.We2, a.Wt1,
        a.kB, a.vB, nullptr, dg, jc, ev, row0, row, wid, lane, xs);
    __threadfence(); grid.sync();

    layer_app<1, false, true, 896, 256, 128, 256>(a.q, a.kB, a.vB, a.s, a.We1, a.Wt2,
        a.kA, a.vA, nullptr, dg, jc, ev, row0, row, wid, lane, xs);
    __threadfence(); grid.sync();

    layer_app<2, true, false, 512, 128, 256, 128>(a.q, a.kA, a.vA, a.s, a.We2, a.Wt1,
        a.kB, a.vB, nullptr, dg, jc, ev, row0, row, wid, lane, xs);
    __threadfence(); grid.sync();

    layer_app<1, false, true, 896, 256, 128, 256>(a.q, a.kB, a.vB, a.s, a.We1, a.Wt2,
        a.kA, a.vA, nullptr, dg, jc, ev, row0, row, wid, lane, xs);
    __threadfence(); grid.sync();

    layer_app<2, true, false, 0, 0, 256, 0>(a.q, a.kA, a.vA, a.s, a.We2, nullptr,
        nullptr, nullptr, a.out, dg, jc, ev, row0, row, wid, lane, xs);
}

// ---------------------------------------------------------------------------
extern "C" void kernel_launch(void* const* d_in, const int* in_sizes, int n_in,
                              void* d_out, int out_size, void* d_ws, size_t ws_size,
                              hipStream_t stream)
{
    // workspace carve (~18.4 MiB): q 4, s 2, kA/vA 8, kB/vB 4, Wt 0.35
    char* p = (char*)d_ws;
    float* q  = (float*)p; p += (size_t)BN * QSTR * 4;
    float* s  = (float*)p; p += (size_t)BN * SSTR * 4;
    float* kA = (float*)p; p += (size_t)BN * 256 * 4;
    float* vA = (float*)p; p += (size_t)BN * 256 * 4;
    float* kB = (float*)p; p += (size_t)BN * 128 * 4;
    float* vB = (float*)p; p += (size_t)BN * 128 * 4;
    __hip_bfloat16* Wt1 = (__hip_bfloat16*)p; p += (size_t)512 * DD * 2;
    __hip_bfloat16* Wt2 = (__hip_bfloat16*)p; p += (size_t)896 * DD * 2;

    MegaArgs margs;
    margs.node = (const float*)d_in[0];
    margs.edge = (const float*)d_in[1];
    margs.A    = (const float*)d_in[2];
    margs.Wq0 = (const float*)d_in[3];  margs.Wk0 = (const float*)d_in[4];
    margs.Wv0 = (const float*)d_in[5];  margs.We0 = (const float*)d_in[6];
    margs.Ws0 = (const float*)d_in[7];
    margs.Wq1 = (const float*)d_in[8];  margs.Wk1 = (const float*)d_in[9];
    margs.Wv1 = (const float*)d_in[10]; margs.We1 = (const float*)d_in[11];
    margs.Ws1 = (const float*)d_in[12];
    margs.Wq2 = (const float*)d_in[13]; margs.Wk2 = (const float*)d_in[14];
    margs.Wv2 = (const float*)d_in[15]; margs.We2 = (const float*)d_in[16];
    margs.Ws2 = (const float*)d_in[17];
    margs.q = q; margs.s = s; margs.kA = kA; margs.vA = vA; margs.kB = kB; margs.vB = vB;
    margs.Wt1 = Wt1; margs.Wt2 = Wt2;
    margs.out = (float*)d_out;

    void* kp[1] = { &margs };
    hipLaunchCooperativeKernel((const void*)mega, dim3(256), dim3(1024), kp, 0, stream);
}

// Round 4
// 334.385 us; speedup vs baseline: 3.8871x; 3.8871x over previous
//
#include <hip/hip_runtime.h>
#include <hip/hip_bf16.h>

#define BB 2
#define NN 2048
#define DD 128
#define BN (BB*NN)
#define CAP 128
#define TD 16
#define QSTR 256
#define SSTR 128
#define INV_SQRT_D 0.08838834764831845f

typedef __attribute__((ext_vector_type(8))) short short8;
typedef __attribute__((ext_vector_type(4))) float f32x4;

__device__ inline float b2f(unsigned short u) {
    union { unsigned int i; float f; } c; c.i = (unsigned int)u << 16; return c.f;
}
__device__ inline float b2f_hi(unsigned int raw) {          // high bf16 of a packed pair
    union { unsigned int i; float f; } c; c.i = raw & 0xffff0000u; return c.f;
}
__device__ inline float b2f_lo(unsigned int raw) {          // low bf16 of a packed pair
    union { unsigned int i; float f; } c; c.i = raw << 16; return c.f;
}

// ---------------------------------------------------------------------------
// LDS-tiled CSR build of e_t[b,dst,src] = edge[b,src,dst]*A[b,src,dst].
// cols[] stores GLOBAL src row (b*NN + src) as ushort. (verified)
// ---------------------------------------------------------------------------
__global__ __launch_bounds__(256) void build_csr(
    const float* __restrict__ A,
    const float* __restrict__ edge,
    int* __restrict__ deg, unsigned short* __restrict__ cols,
    float* __restrict__ evals)
{
    __shared__ int   cnt[TD];
    __shared__ int   csh[TD][CAP];
    __shared__ float esh[TD][CAP];

    int bid  = blockIdx.x;
    int b    = bid / (NN / TD);
    int dst0 = (bid % (NN / TD)) * TD;
    int tid  = threadIdx.x;

    if (tid < TD) cnt[tid] = 0;
    __syncthreads();

    int srcOff = tid >> 2;
    int dOff   = (tid & 3) * 4;
    const size_t base = (size_t)b * NN * NN + dst0 + dOff;

#pragma unroll 2
    for (int s0 = 0; s0 < NN; s0 += 64) {
        int src = s0 + srcOff;
        float4 a4 = *(const float4*)&A[base + (size_t)src * NN];
        float4 e4 = *(const float4*)&edge[base + (size_t)src * NN];
        int gsrc = b * NN + src;
        float av[4] = {a4.x, a4.y, a4.z, a4.w};
        float ev[4] = {e4.x, e4.y, e4.z, e4.w};
#pragma unroll
        for (int u = 0; u < 4; u++) {
            if (av[u] != 0.f) {
                int d = dOff + u;
                int slot = atomicAdd(&cnt[d], 1);
                if (slot < CAP) { csh[d][slot] = gsrc; esh[d][slot] = ev[u] * av[u]; }
            }
        }
    }
    __syncthreads();

    if (tid < TD) deg[b * NN + dst0 + tid] = min(cnt[tid], CAP);
    for (int idx = tid; idx < TD * CAP; idx += 256) {
        int d = idx / CAP, i = idx % CAP;
        if (i < min(cnt[d], CAP)) {
            size_t row = (size_t)(b * NN + dst0 + d);
            cols [row * CAP + i] = (unsigned short)csh[d][i];
            evals[row * CAP + i] = esh[d][i];
        }
    }
}

// ---------------------------------------------------------------------------
// Merged setup: weight transposes + layer-0 rank-1 projection.
// q/s written fp32; kA/vA written bf16.
// ---------------------------------------------------------------------------
__global__ __launch_bounds__(128) void setup_small(
    const float* __restrict__ node,
    const float* __restrict__ Wq0, const float* __restrict__ Wk0,
    const float* __restrict__ Wv0, const float* __restrict__ Ws0,
    const float* __restrict__ Wq1, const float* __restrict__ Wk1,
    const float* __restrict__ Wv1, const float* __restrict__ Ws1,
    const float* __restrict__ Wq2, const float* __restrict__ Wk2,
    const float* __restrict__ Wv2, const float* __restrict__ Ws2,
    __hip_bfloat16* __restrict__ Wt1, __hip_bfloat16* __restrict__ Wt2,
    float* __restrict__ q, __hip_bfloat16* __restrict__ kA,
    __hip_bfloat16* __restrict__ vA, float* __restrict__ s)
{
    __shared__ float xs[16];
    int bid = blockIdx.x;
    int t   = threadIdx.x;

    if (bid < 1408) {
        const float *Wq, *Wk, *Wv, *Ws; __hip_bfloat16* Wt; int n, HD;
        if (bid < 512) { Wq = Wq1; Wk = Wk1; Wv = Wv1; Ws = Ws1; Wt = Wt1; n = bid;       HD = DD;     }
        else           { Wq = Wq2; Wk = Wk2; Wv = Wv2; Ws = Ws2; Wt = Wt2; n = bid - 512; HD = 2 * DD; }
        const float* src; int ld; int col;
        if      (n < HD)     { src = Wq; col = n;          ld = HD; }
        else if (n < 2*HD)   { src = Wk; col = n - HD;     ld = HD; }
        else if (n < 3*HD)   { src = Wv; col = n - 2*HD;   ld = HD; }
        else                 { src = Ws; col = n - 3*HD;   ld = DD; }
        Wt[(size_t)n * DD + t] = __float2bfloat16(src[(size_t)t * ld + col]);
    } else {
        int pb   = bid - 1408;
        int row0 = (pb & (BN / 16 - 1)) * 16;
        int gy   = pb / (BN / 16);
        if (t < 16) xs[t] = node[row0 + t];
        __syncthreads();
        int col = gy * 128 + t;
        if (col < DD) {
            float wf = Wq0[col];
#pragma unroll
            for (int r = 0; r < 16; r++) q[(size_t)(row0 + r) * QSTR + col] = xs[r] * wf;
        } else if (col < 2*DD) {
            int lc = col - DD; float wf = Wk0[lc];
#pragma unroll
            for (int r = 0; r < 16; r++) kA[(size_t)(row0 + r) * 256 + lc] = __float2bfloat16(xs[r] * wf);
        } else if (col < 3*DD) {
            int lc = col - 2*DD; float wf = Wv0[lc];
#pragma unroll
            for (int r = 0; r < 16; r++) vA[(size_t)(row0 + r) * 256 + lc] = __float2bfloat16(xs[r] * wf);
        } else {
            int lc = col - 3*DD; float wf = Ws0[lc];
#pragma unroll
            for (int r = 0; r < 16; r++) s[(size_t)(row0 + r) * SSTR + lc] = xs[r] * wf;
        }
    }
}

// ---------------------------------------------------------------------------
// Fused sparse attention + next-layer projection (round-2 structure).
// k/v are now bf16: halves gather bytes and makes the H=2 k+v set (4 MB)
// fit per-XCD L2 (was 8 MB fp32 -> LLC thrash).
// q/skip fp32, updated in place (own-row only, drained before the barrier).
//   NCOLS == 0 -> final layer, write fp32 to out.
// ---------------------------------------------------------------------------
template<int H, bool MEANH, bool LNRELU, int NCOLS, int HDN, int KVSI, int KVSO>
__global__ __launch_bounds__(1024) void fused_attn(
    float* qio,                                   // in/out, stride QSTR
    const __hip_bfloat16* __restrict__ k,         // stride KVSI
    const __hip_bfloat16* __restrict__ v,         // stride KVSI
    float* sio,                                   // in/out, stride SSTR
    const int* __restrict__ deg,
    const unsigned short* __restrict__ cols,
    const float* __restrict__ evals, const float* __restrict__ We,
    const __hip_bfloat16* __restrict__ Wt,
    __hip_bfloat16* __restrict__ kn, __hip_bfloat16* __restrict__ vn, // stride KVSO
    float* __restrict__ out)
{
    const int HD = H * DD;
    int wid  = threadIdx.x >> 6;       // 0..15
    int lane = threadIdx.x & 63;
    int row0 = blockIdx.x * 16;
    int row  = row0 + wid;
    int sub  = lane >> 4;
    int s    = lane & 15;
    int c0   = lane * 2;

    __shared__ int            jc_s[16][CAP];
    __shared__ float          ev_s[16][CAP];
    __shared__ __hip_bfloat16 xs[16][136];   // +8 bf16 pad (16B-aligned rows)
    int*   jc = jc_s[wid];
    float* ev = ev_s[wid];

    int dg = min(deg[row], CAP);
    for (int m = lane; m < dg; m += 64) {
        jc[m] = (int)cols[(size_t)row * CAP + m];
        ev[m] = evals[(size_t)row * CAP + m];
    }
    // wave-private LDS: no barrier needed (compiler inserts lgkmcnt waits)

    float qh[H][8];
    float qeI[H];
#pragma unroll
    for (int h = 0; h < H; h++) {
        const float* qp = &qio[(size_t)row * QSTR + h * DD + s * 8];
        const float* wp = &We[h * DD + s * 8];
        float pe = 0.f;
#pragma unroll
        for (int t = 0; t < 8; t++) { qh[h][t] = qp[t]; pe += qp[t] * wp[t]; }
#pragma unroll
        for (int off = 1; off < 16; off <<= 1) pe += __shfl_xor(pe, off);
        qeI[h] = pe * INV_SQRT_D;
    }

    float l_acc[H], ew_acc[H], acc[H][2];
#pragma unroll
    for (int h = 0; h < H; h++) { l_acc[h] = 0.f; ew_acc[h] = 0.f; acc[h][0] = 0.f; acc[h][1] = 0.f; }

    for (int m0 = 0; m0 < dg; m0 += 4) {
        int   e  = m0 + sub;
        bool  ok = e < dg;
        int   ec = ok ? e : m0;
        int   j  = jc[ec];
        float ee = ev[ec];

        int jb[4];
#pragma unroll
        for (int es = 0; es < 4; es++) jb[es] = jc[(m0 + es < dg) ? m0 + es : m0];
        // packed bf16 pair loads for v (4 B per edge per head per lane)
        unsigned int vraw[H][4];
#pragma unroll
        for (int h = 0; h < H; h++)
#pragma unroll
            for (int es = 0; es < 4; es++)
                vraw[h][es] = *(const unsigned int*)&v[(size_t)jb[es] * KVSI + h * DD + c0];

#pragma unroll
        for (int h = 0; h < H; h++) {
            const short8 k8 = *(const short8*)&k[(size_t)j * KVSI + h * DD + s * 8];
            float p = qh[h][0]*b2f((unsigned short)k8[0]) + qh[h][1]*b2f((unsigned short)k8[1])
                    + qh[h][2]*b2f((unsigned short)k8[2]) + qh[h][3]*b2f((unsigned short)k8[3])
                    + qh[h][4]*b2f((unsigned short)k8[4]) + qh[h][5]*b2f((unsigned short)k8[5])
                    + qh[h][6]*b2f((unsigned short)k8[6]) + qh[h][7]*b2f((unsigned short)k8[7]);
#pragma unroll
            for (int off = 1; off < 16; off <<= 1) p += __shfl_xor(p, off);
            float sc = ok ? (p * INV_SQRT_D + qeI[h] * ee) : -1e30f;
            float a4 = __expf(fminf(sc, 60.f));       // invalid -> exp(-1e30)=0
            l_acc[h]  += a4;                          // subgroup-local (x16 replicated)
            ew_acc[h] += a4 * ee;
            float al[4];
#pragma unroll
            for (int es = 0; es < 4; es++) al[es] = __shfl(a4, es * 16);
#pragma unroll
            for (int es = 0; es < 4; es++) {
                acc[h][0] += al[es] * b2f_lo(vraw[h][es]);
                acc[h][1] += al[es] * b2f_hi(vraw[h][es]);
            }
        }
    }

    // reduce l/ew across the 4 subgroups (values replicated within subgroup)
    float rh[H][2];
#pragma unroll
    for (int h = 0; h < H; h++) {
        float l  = l_acc[h]  + __shfl_xor(l_acc[h], 16);
        float ew = ew_acc[h] + __shfl_xor(ew_acc[h], 16);
        l  += __shfl_xor(l, 32);
        ew += __shfl_xor(ew, 32);
        float invZ = (l > 0.f) ? 1.f / l : 0.f;
        rh[h][0] = (acc[h][0] + ew * We[h * DD + c0])     * invZ;
        rh[h][1] = (acc[h][1] + ew * We[h * DD + c0 + 1]) * invZ;
    }
    float r0, r1;
    if constexpr (MEANH) {
        r0 = 0.5f * (rh[0][0] + rh[H - 1][0]);
        r1 = 0.5f * (rh[0][1] + rh[H - 1][1]);
    } else {
        r0 = rh[0][0]; r1 = rh[0][1];
    }
    float2 sk = *(const float2*)&sio[(size_t)row * SSTR + c0];
    r0 += sk.x; r1 += sk.y;

    if constexpr (LNRELU) {
        float sum = r0 + r1, sq = r0 * r0 + r1 * r1;
#pragma unroll
        for (int off = 32; off; off >>= 1) { sum += __shfl_xor(sum, off); sq += __shfl_xor(sq, off); }
        float mu  = sum * (1.f / DD);
        float var = sq * (1.f / DD) - mu * mu;
        float rs  = rsqrtf(var + 1e-5f);
        r0 = fmaxf((r0 - mu) * rs, 0.f);
        r1 = fmaxf((r1 - mu) * rs, 0.f);
    }

    if constexpr (NCOLS == 0) {
        float2 res; res.x = r0; res.y = r1;
        *(float2*)&out[(size_t)row * DD + c0] = res;
    } else {
        // stage bf16 x-tile in LDS, then MFMA-project into next-layer buffers
        __hip_bfloat162 o;
        o.x = __float2bfloat16(r0);
        o.y = __float2bfloat16(r1);
        *(__hip_bfloat162*)&xs[wid][c0] = o;
        __syncthreads();   // all attn reads (q/skip/k/v) drained before writes

        int m16 = lane & 15, quad = lane >> 4;
        short8 a[4];
#pragma unroll
        for (int ks = 0; ks < 4; ks++)
            a[ks] = *(const short8*)&xs[m16][ks * 32 + quad * 8];

#pragma unroll 1
        for (int tile = wid; tile < NCOLS / 16; tile += 16) {
            int n0 = tile * 16;
            f32x4 pacc = {0.f, 0.f, 0.f, 0.f};
#pragma unroll
            for (int ks = 0; ks < 4; ks++) {
                const short8* bp = (const short8*)&Wt[(size_t)(n0 + m16) * DD + ks * 32 + quad * 8];
                pacc = __builtin_amdgcn_mfma_f32_16x16x32_bf16(a[ks], *bp, pacc, 0, 0, 0);
            }
            if (n0 < HDN) {                                   // q: fp32 in place
#pragma unroll
                for (int r = 0; r < 4; r++)
                    qio[(size_t)(row0 + quad * 4 + r) * QSTR + n0 + m16] = pacc[r];
            } else if (n0 < 2*HDN) {                          // k: bf16
                int lc = n0 - HDN;
#pragma unroll
                for (int r = 0; r < 4; r++)
                    kn[(size_t)(row0 + quad * 4 + r) * KVSO + lc + m16] = __float2bfloat16(pacc[r]);
            } else if (n0 < 3*HDN) {                          // v: bf16
                int lc = n0 - 2*HDN;
#pragma unroll
                for (int r = 0; r < 4; r++)
                    vn[(size_t)(row0 + quad * 4 + r) * KVSO + lc + m16] = __float2bfloat16(pacc[r]);
            } else {                                          // skip: fp32 in place
                int lc = n0 - 3*HDN;
#pragma unroll
                for (int r = 0; r < 4; r++)
                    sio[(size_t)(row0 + quad * 4 + r) * SSTR + lc + m16] = pacc[r];
            }
        }
    }
}

// ---------------------------------------------------------------------------
extern "C" void kernel_launch(void* const* d_in, const int* in_sizes, int n_in,
                              void* d_out, int out_size, void* d_ws, size_t ws_size,
                              hipStream_t stream)
{
    const float* node = (const float*)d_in[0];
    const float* edge = (const float*)d_in[1];
    const float* A    = (const float*)d_in[2];
    const float* Wq[3] = {(const float*)d_in[3],  (const float*)d_in[8],  (const float*)d_in[13]};
    const float* Wk[3] = {(const float*)d_in[4],  (const float*)d_in[9],  (const float*)d_in[14]};
    const float* Wv[3] = {(const float*)d_in[5],  (const float*)d_in[10], (const float*)d_in[15]};
    const float* We[3] = {(const float*)d_in[6],  (const float*)d_in[11], (const float*)d_in[16]};
    const float* Ws[3] = {(const float*)d_in[7],  (const float*)d_in[12], (const float*)d_in[17]};

    // workspace carve (~15.4 MiB):
    //   q fp32 (stride 256) 4 MiB | s fp32 2 MiB
    //   kA/vA bf16 (stride 256) 4 MiB | kB/vB bf16 (stride 128) 2 MiB
    //   Wt 0.35 MiB | deg/cols(u16)/evals 3.02 MiB
    char* p = (char*)d_ws;
    float*          q  = (float*)p;          p += (size_t)BN * QSTR * 4;
    float*          s  = (float*)p;          p += (size_t)BN * SSTR * 4;
    __hip_bfloat16* kA = (__hip_bfloat16*)p; p += (size_t)BN * 256 * 2;
    __hip_bfloat16* vA = (__hip_bfloat16*)p; p += (size_t)BN * 256 * 2;
    __hip_bfloat16* kB = (__hip_bfloat16*)p; p += (size_t)BN * 128 * 2;
    __hip_bfloat16* vB = (__hip_bfloat16*)p; p += (size_t)BN * 128 * 2;
    __hip_bfloat16* Wt1 = (__hip_bfloat16*)p; p += (size_t)512 * DD * 2;
    __hip_bfloat16* Wt2 = (__hip_bfloat16*)p; p += (size_t)896 * DD * 2;
    int*            degb = (int*)p;            p += (size_t)BN * 4;
    float*          evb  = (float*)p;          p += (size_t)BN * CAP * 4;
    unsigned short* colb = (unsigned short*)p; p += (size_t)BN * CAP * 2;

    build_csr<<<BB * (NN / TD), 256, 0, stream>>>(A, edge, degb, colb, evb);
    setup_small<<<2432, 128, 0, stream>>>(node,
        Wq[0], Wk[0], Wv[0], Ws[0],
        Wq[1], Wk[1], Wv[1], Ws[1],
        Wq[2], Wk[2], Wv[2], Ws[2],
        Wt1, Wt2, q, kA, vA, s);

    // app sequence l = {0,1,2,1,2,1,2}; each kernel = attn(l) + proj(next l)
    fused_attn<1, false, true, 512, 128, 256, 128><<<BN / 16, 1024, 0, stream>>>(   // l0 -> proj l1
        q, kA, vA, s, degb, colb, evb, We[0], Wt1, kB, vB, nullptr);
    fused_attn<1, false, true, 896, 256, 128, 256><<<BN / 16, 1024, 0, stream>>>(   // l1 -> proj l2
        q, kB, vB, s, degb, colb, evb, We[1], Wt2, kA, vA, nullptr);
    fused_attn<2, true, false, 512, 128, 256, 128><<<BN / 16, 1024, 0, stream>>>(   // l2 -> proj l1
        q, kA, vA, s, degb, colb, evb, We[2], Wt1, kB, vB, nullptr);
    fused_attn<1, false, true, 896, 256, 128, 256><<<BN / 16, 1024, 0, stream>>>(   // l1 -> proj l2
        q, kB, vB, s, degb, colb, evb, We[1], Wt2, kA, vA, nullptr);
    fused_attn<2, true, false, 512, 128, 256, 128><<<BN / 16, 1024, 0, stream>>>(   // l2 -> proj l1
        q, kA, vA, s, degb, colb, evb, We[2], Wt1, kB, vB, nullptr);
    fused_attn<1, false, true, 896, 256, 128, 256><<<BN / 16, 1024, 0, stream>>>(   // l1 -> proj l2
        q, kB, vB, s, degb, colb, evb, We[1], Wt2, kA, vA, nullptr);
    fused_attn<2, true, false, 0, 0, 256, 0><<<BN / 16, 1024, 0, stream>>>(         // l2 -> output
        q, kA, vA, s, degb, colb, evb, We[2], nullptr, nullptr, nullptr, (float*)d_out);
}